// Round 1
// baseline (238.070 us; speedup 1.0000x reference)
//
#include <hip/hip_runtime.h>

// DWT 1D (8-tap biorthogonal-style taps), stride-2 banded conv.
// x: (16,64,8192) f32.  out = [lo (16,64,4096) | hi (16,64,4096)] f32.
// lo[k] = sum_j LO[j] * x[2k + j - 3], taps outside [0,8192) dropped.

#define SEQ   8192
#define HALF  4096
#define ROWS  (16 * 64)

__global__ __launch_bounds__(256) void dwt1d_kernel(const float* __restrict__ x,
                                                    float* __restrict__ out) {
    constexpr float LO[8] = {
        0.23037781330885523f,  0.7148465705525415f,  0.6308807679295904f,
       -0.02798376941698385f, -0.18703481171888114f, 0.030841381835986965f,
        0.032883011666982945f, -0.010597401784997278f};
    constexpr float HI[8] = {
       -0.010597401784997278f, -0.032883011666982945f, 0.030841381835986965f,
        0.18703481171888114f,  -0.02798376941698385f, -0.6308807679295904f,
        0.7148465705525415f,   -0.23037781330885523f};

    const int g   = blockIdx.x * 256 + threadIdx.x;  // one thread = 4 k-positions
    const int k4  = g & 1023;                        // float4 group within row
    const int row = g >> 10;                         // (n*64 + c)

    const float* __restrict__ xr = x + (size_t)row * SEQ;
    const int base = 8 * k4 - 4;                     // first input index of v[16]

    float v[16];
    if (k4 != 0 && k4 != 1023) {
        // base >= 4, base+15 <= 8187; base % 4 == 0 -> aligned float4 loads
        const float4* p = (const float4*)(xr + base);
        float4 a = p[0], b = p[1], c = p[2], d = p[3];
        v[0]=a.x;  v[1]=a.y;  v[2]=a.z;  v[3]=a.w;
        v[4]=b.x;  v[5]=b.y;  v[6]=b.z;  v[7]=b.w;
        v[8]=c.x;  v[9]=c.y;  v[10]=c.z; v[11]=c.w;
        v[12]=d.x; v[13]=d.y; v[14]=d.z; v[15]=d.w;
    } else {
        // row edges: zero-fill out-of-range taps (reproduces band truncation)
        #pragma unroll
        for (int m = 0; m < 16; ++m) {
            const int idx = base + m;
            v[m] = (idx >= 0 && idx < SEQ) ? xr[idx] : 0.0f;
        }
    }

    float lo[4], hi[4];
    #pragma unroll
    for (int i = 0; i < 4; ++i) {
        float accl = 0.0f, acch = 0.0f;
        #pragma unroll
        for (int j = 0; j < 8; ++j) {
            // x index = 2*(4*k4+i) + j - 3 = base + (2*i + j + 1)
            const float xv = v[2 * i + j + 1];
            accl = fmaf(LO[j], xv, accl);
            acch = fmaf(HI[j], xv, acch);
        }
        lo[i] = accl;
        hi[i] = acch;
    }

    float* __restrict__ lo_out = out + (size_t)row * HALF;
    float* __restrict__ hi_out = out + (size_t)ROWS * HALF + (size_t)row * HALF;
    ((float4*)lo_out)[k4] = make_float4(lo[0], lo[1], lo[2], lo[3]);
    ((float4*)hi_out)[k4] = make_float4(hi[0], hi[1], hi[2], hi[3]);
}

extern "C" void kernel_launch(void* const* d_in, const int* in_sizes, int n_in,
                              void* d_out, int out_size, void* d_ws, size_t ws_size,
                              hipStream_t stream) {
    const float* x = (const float*)d_in[0];
    float* out = (float*)d_out;
    // total threads = ROWS * (HALF/4) = 1024 * 1024 = 1,048,576 -> 4096 blocks
    const int total = ROWS * (HALF / 4);
    dwt1d_kernel<<<total / 256, 256, 0, stream>>>(x, out);
}

// Round 3
// 237.421 us; speedup vs baseline: 1.0027x; 1.0027x over previous
//
#include <hip/hip_runtime.h>

// DWT 1D (8-tap), stride-2 banded conv.
// x: (16,64,8192) f32.  out = [lo (16,64,4096) | hi (16,64,4096)] f32.
// lo[k] = sum_j LO[j] * x[2k + j - 3], taps outside [0,8192) dropped.
//
// Memory-bound: 33.5 MB read + 33.5 MB write. One thread = 4 outputs per
// band; 4 aligned float4 loads cover the 16-float support exactly.
// Outputs are write-only -> non-temporal stores keep L2 for the input.

#define SEQ   8192
#define HALF  4096
#define ROWS  (16 * 64)

typedef float v4f __attribute__((ext_vector_type(4)));

__global__ __launch_bounds__(256) void dwt1d_kernel(const float* __restrict__ x,
                                                    float* __restrict__ out) {
    constexpr float LO[8] = {
        0.23037781330885523f,  0.7148465705525415f,  0.6308807679295904f,
       -0.02798376941698385f, -0.18703481171888114f, 0.030841381835986965f,
        0.032883011666982945f, -0.010597401784997278f};
    constexpr float HI[8] = {
       -0.010597401784997278f, -0.032883011666982945f, 0.030841381835986965f,
        0.18703481171888114f,  -0.02798376941698385f, -0.6308807679295904f,
        0.7148465705525415f,   -0.23037781330885523f};

    const int g   = blockIdx.x * 256 + threadIdx.x;  // one thread = 4 k-positions
    const int k4  = g & 1023;                        // float4 group within row
    const int row = g >> 10;                         // (n*64 + c)

    const float* __restrict__ xr = x + (size_t)row * SEQ;
    const int base = 8 * k4 - 4;                     // first input index of v[16]

    float v[16];
    if (k4 != 0 && k4 != 1023) {
        // base >= 4, base+15 <= 8187; 16B-aligned vector loads
        const v4f* p = (const v4f*)(xr + base);
        v4f a = p[0], b = p[1], c = p[2], d = p[3];
        v[0]=a.x;  v[1]=a.y;  v[2]=a.z;  v[3]=a.w;
        v[4]=b.x;  v[5]=b.y;  v[6]=b.z;  v[7]=b.w;
        v[8]=c.x;  v[9]=c.y;  v[10]=c.z; v[11]=c.w;
        v[12]=d.x; v[13]=d.y; v[14]=d.z; v[15]=d.w;
    } else {
        // row edges: zero-fill out-of-range taps (reproduces band truncation)
        #pragma unroll
        for (int m = 0; m < 16; ++m) {
            const int idx = base + m;
            v[m] = (idx >= 0 && idx < SEQ) ? xr[idx] : 0.0f;
        }
    }

    float lo[4], hi[4];
    #pragma unroll
    for (int i = 0; i < 4; ++i) {
        float accl = 0.0f, acch = 0.0f;
        #pragma unroll
        for (int j = 0; j < 8; ++j) {
            // x index = 2*(4*k4+i) + j - 3 = base + (2*i + j + 1)
            const float xv = v[2 * i + j + 1];
            accl = fmaf(LO[j], xv, accl);
            acch = fmaf(HI[j], xv, acch);
        }
        lo[i] = accl;
        hi[i] = acch;
    }

    v4f* lo_out = (v4f*)(out + (size_t)row * HALF) + k4;
    v4f* hi_out = (v4f*)(out + (size_t)ROWS * HALF + (size_t)row * HALF) + k4;
    v4f lov = {lo[0], lo[1], lo[2], lo[3]};
    v4f hiv = {hi[0], hi[1], hi[2], hi[3]};
    __builtin_nontemporal_store(lov, lo_out);
    __builtin_nontemporal_store(hiv, hi_out);
}

extern "C" void kernel_launch(void* const* d_in, const int* in_sizes, int n_in,
                              void* d_out, int out_size, void* d_ws, size_t ws_size,
                              hipStream_t stream) {
    const float* x = (const float*)d_in[0];
    float* out = (float*)d_out;
    // total threads = ROWS * (HALF/4) = 1024 * 1024 -> 4096 blocks of 256
    const int total = ROWS * (HALF / 4);
    dwt1d_kernel<<<total / 256, 256, 0, stream>>>(x, out);
}